// Round 1
// baseline (1506.984 us; speedup 1.0000x reference)
//
#include <hip/hip_runtime.h>
#include <hip/hip_bf16.h>
#include <math.h>

#define N_NODES 50000
#define N_EDGES 800000

// ----------------- preprocessing: degree + CSR build -----------------

__global__ void count_kernel(const int* __restrict__ col, int* __restrict__ cnt, int E) {
  int e = blockIdx.x * blockDim.x + threadIdx.x;
  if (e < E) atomicAdd(&cnt[col[e]], 1);
}

__global__ void dinv_kernel(const int* __restrict__ cnt, float* __restrict__ dinv, int n) {
  int j = blockIdx.x * blockDim.x + threadIdx.x;
  if (j < n) dinv[j] = 1.0f / sqrtf((float)(cnt[j] + 1));  // +1 self-loop; deg>=1 always
}

// exclusive scan, 256/block, two-level (N=50000 -> 196 block sums)
__global__ void scan_block_kernel(const int* __restrict__ in, int* __restrict__ out,
                                  int* __restrict__ bsums, int n) {
  __shared__ int s[256];
  int gid = blockIdx.x * 256 + threadIdx.x;
  int v = (gid < n) ? in[gid] : 0;
  s[threadIdx.x] = v;
  __syncthreads();
  for (int off = 1; off < 256; off <<= 1) {
    int t = (threadIdx.x >= off) ? s[threadIdx.x - off] : 0;
    __syncthreads();
    s[threadIdx.x] += t;
    __syncthreads();
  }
  if (gid < n) out[gid] = s[threadIdx.x] - v;  // exclusive
  if (threadIdx.x == 255) bsums[blockIdx.x] = s[255];
}

__global__ void scan_top_kernel(int* __restrict__ bsums, int n) {
  __shared__ int s[256];
  int v = (threadIdx.x < n) ? bsums[threadIdx.x] : 0;
  s[threadIdx.x] = v;
  __syncthreads();
  for (int off = 1; off < 256; off <<= 1) {
    int t = (threadIdx.x >= off) ? s[threadIdx.x - off] : 0;
    __syncthreads();
    s[threadIdx.x] += t;
    __syncthreads();
  }
  if (threadIdx.x < n) bsums[threadIdx.x] = s[threadIdx.x] - v;  // exclusive
}

__global__ void scan_add_kernel(int* __restrict__ row_ptr, int* __restrict__ fill,
                                const int* __restrict__ bsums, int n) {
  int gid = blockIdx.x * 256 + threadIdx.x;
  if (gid < n) {
    int v = row_ptr[gid] + bsums[blockIdx.x];
    row_ptr[gid] = v;
    fill[gid] = v;  // atomic cursor copy for the fill pass
  }
}

__global__ void fill_kernel(const int* __restrict__ row, const int* __restrict__ col,
                            int* __restrict__ fill, int* __restrict__ srcs, int E) {
  int e = blockIdx.x * blockDim.x + threadIdx.x;
  if (e < E) {
    int d = col[e];
    int pos = atomicAdd(&fill[d], 1);
    srcs[pos] = row[e];
  }
}

// ----------------- fp32 tiled GEMM: C[M,Nc] = A[M,K] @ W[K,Nc] -----------------
// 128x128 block tile, BK=16, 256 threads, 8x8 per-thread microtile.
// FLOP : LDS-byte = 2.0 -> balanced against the 128 B/cy/CU LDS roofline.

#define BM 128
#define BN 128
#define BK 16

__global__ __launch_bounds__(256) void gemm_kernel(
    const float* __restrict__ A, const float* __restrict__ W,
    float* __restrict__ C, int M, int K, int Nc) {
  __shared__ float As[BK][BM + 4];  // stored transposed: As[k][m]
  __shared__ float Bs[BK][BN + 4];
  int tid = threadIdx.x;
  int bm = blockIdx.x * BM;
  int bn = blockIdx.y * BN;
  int tx = tid & 15;   // col group -> cols tx*8 .. +7
  int ty = tid >> 4;   // row group -> rows ty*8 .. +7
  float acc[8][8] = {};

  for (int k0 = 0; k0 < K; k0 += BK) {
    // stage A tile (128 rows x 16 k), transpose into As[k][m]
#pragma unroll
    for (int i = 0; i < 2; ++i) {
      int idx = tid + i * 256;
      int r = idx >> 2;           // 0..127
      int kc = (idx & 3) * 4;     // 0,4,8,12
      int gr = bm + r;
      float4 v = make_float4(0.f, 0.f, 0.f, 0.f);
      if (gr < M) v = *(const float4*)(A + (size_t)gr * K + k0 + kc);
      As[kc + 0][r] = v.x; As[kc + 1][r] = v.y; As[kc + 2][r] = v.z; As[kc + 3][r] = v.w;
    }
    // stage B tile (16 k x 128 cols)
#pragma unroll
    for (int i = 0; i < 2; ++i) {
      int idx = tid + i * 256;
      int k = idx >> 5;           // 0..15
      int cc = (idx & 31) * 4;    // 0..124
      float4 v = make_float4(0.f, 0.f, 0.f, 0.f);
      if (bn + cc < Nc) v = *(const float4*)(W + (size_t)(k0 + k) * Nc + bn + cc);
      *(float4*)&Bs[k][cc] = v;
    }
    __syncthreads();
#pragma unroll
    for (int kk = 0; kk < BK; ++kk) {
      float a[8], b[8];
      *(float4*)&a[0] = *(const float4*)&As[kk][ty * 8];
      *(float4*)&a[4] = *(const float4*)&As[kk][ty * 8 + 4];
      *(float4*)&b[0] = *(const float4*)&Bs[kk][tx * 8];
      *(float4*)&b[4] = *(const float4*)&Bs[kk][tx * 8 + 4];
#pragma unroll
      for (int i = 0; i < 8; ++i)
#pragma unroll
        for (int j = 0; j < 8; ++j)
          acc[i][j] += a[i] * b[j];
    }
    __syncthreads();
  }

#pragma unroll
  for (int i = 0; i < 8; ++i) {
    int gr = bm + ty * 8 + i;
    if (gr < M) {
#pragma unroll
      for (int jc = 0; jc < 2; ++jc) {
        int gc = bn + tx * 8 + jc * 4;
        if (gc < Nc) {
          float4 v = make_float4(acc[i][jc * 4 + 0], acc[i][jc * 4 + 1],
                                 acc[i][jc * 4 + 2], acc[i][jc * 4 + 3]);
          *(float4*)(C + (size_t)gr * Nc + gc) = v;
        }
      }
    }
  }
}

// ----------------- pull-style aggregation -----------------
// out[j] = dinv[j] * ( sum_{e: dst=j} t[src]*dinv[src] + t[j]*dinv[j] ) + bias; optional ReLU.
// One wave per node; VW=4 -> D=256 (float4/lane), VW=1 -> D=64 (scalar/lane).

template <int VW, bool RELU>
__global__ __launch_bounds__(64) void aggregate_kernel(
    const float* __restrict__ t, float* __restrict__ out,
    const int* __restrict__ row_ptr, const int* __restrict__ cnt,
    const int* __restrict__ srcs, const float* __restrict__ dinv,
    const float* __restrict__ bias, int D) {
  int j = blockIdx.x;
  int lane = threadIdx.x;
  int base = lane * VW;
  int start = row_ptr[j];
  int n = cnt[j];
  float acc[VW];
#pragma unroll
  for (int c = 0; c < VW; ++c) acc[c] = 0.f;

  for (int i = 0; i < n; ++i) {
    int s = srcs[start + i];
    float w = dinv[s];
    const float* p = t + (size_t)s * D + base;
    if (VW == 4) {
      float4 v = *(const float4*)p;
      acc[0] += v.x * w; acc[1] += v.y * w; acc[2] += v.z * w; acc[3] += v.w * w;
    } else {
      acc[0] += p[0] * w;
    }
  }

  float dj = dinv[j];
  const float* pj = t + (size_t)j * D + base;
  float res[VW];
  if (VW == 4) {
    float4 v = *(const float4*)pj;
    float4 bv = *(const float4*)(bias + base);
    res[0] = (acc[0] + v.x * dj) * dj + bv.x;
    res[1] = (acc[1] + v.y * dj) * dj + bv.y;
    res[2] = (acc[2] + v.z * dj) * dj + bv.z;
    res[3] = (acc[3] + v.w * dj) * dj + bv.w;
  } else {
    res[0] = (acc[0] + pj[0] * dj) * dj + bias[base];
  }
#pragma unroll
  for (int c = 0; c < VW; ++c)
    if (RELU) res[c] = fmaxf(res[c], 0.f);

  if (VW == 4) {
    *(float4*)(out + (size_t)j * D + base) = make_float4(res[0], res[1], res[2], res[3]);
  } else {
    out[(size_t)j * D + base] = res[0];
  }
}

// ----------------- final dense layer: sigmoid(H[N,64] @ W4[64,64] + b4) -----------------
// One wave per node; row broadcast via __shfl, W4 cached in LDS.

__global__ __launch_bounds__(256) void final_kernel(
    const float* __restrict__ H, const float* __restrict__ W4,
    const float* __restrict__ b4, float* __restrict__ out, int n) {
  __shared__ float Ws[64 * 64];
  __shared__ float bs[64];
  for (int i = threadIdx.x; i < 64 * 64; i += 256) Ws[i] = W4[i];
  if (threadIdx.x < 64) bs[threadIdx.x] = b4[threadIdx.x];
  __syncthreads();
  int wave = threadIdx.x >> 6;  // 0..3
  int lane = threadIdx.x & 63;
  int node0 = blockIdx.x * 32 + wave;  // 4 waves x 8 iters = 32 nodes/block
  for (int it = 0; it < 8; ++it) {
    int node = node0 + it * 4;
    if (node < n) {
      float a = H[(size_t)node * 64 + lane];
      float acc = bs[lane];
#pragma unroll
      for (int k = 0; k < 64; ++k) {
        float av = __shfl(a, k, 64);
        acc += av * Ws[k * 64 + lane];
      }
      out[(size_t)node * 64 + lane] = 1.0f / (1.0f + expf(-acc));
    }
  }
}

// ----------------- driver -----------------

extern "C" void kernel_launch(void* const* d_in, const int* in_sizes, int n_in,
                              void* d_out, int out_size, void* d_ws, size_t ws_size,
                              hipStream_t stream) {
  const float* x  = (const float*)d_in[0];
  const int* ei   = (const int*)d_in[1];  // JAX w/o x64: int64 request -> int32 array
  const float* W1 = (const float*)d_in[2];
  const float* b1 = (const float*)d_in[3];
  const float* W2 = (const float*)d_in[4];
  const float* b2 = (const float*)d_in[5];
  const float* W3 = (const float*)d_in[6];
  const float* b3 = (const float*)d_in[7];
  const float* W4 = (const float*)d_in[8];
  const float* b4 = (const float*)d_in[9];
  float* outp = (float*)d_out;

  const int N = N_NODES, E = N_EDGES;
  const int* row = ei;       // edge_index[0]
  const int* col = ei + E;   // edge_index[1]

  // workspace layout (~106.4 MB)
  float* A = (float*)d_ws;                   // [N,256] ping
  float* B = A + (size_t)N * 256;            // [N,256] pong
  float* dinv = B + (size_t)N * 256;         // [N]
  int* cnt = (int*)(dinv + N);               // [N] in-degree (excl. self-loop)
  int* row_ptr = cnt + N;                    // [N] CSR offsets
  int* fill = row_ptr + N;                   // [N] atomic cursors
  int* bsums = fill + N;                     // [256]
  int* srcs = bsums + 256;                   // [E] sources sorted by dst

  hipMemsetAsync(cnt, 0, N * sizeof(int), stream);
  count_kernel<<<(E + 255) / 256, 256, 0, stream>>>(col, cnt, E);
  dinv_kernel<<<(N + 255) / 256, 256, 0, stream>>>(cnt, dinv, N);
  int nblk = (N + 255) / 256;  // 196
  scan_block_kernel<<<nblk, 256, 0, stream>>>(cnt, row_ptr, bsums, N);
  scan_top_kernel<<<1, 256, 0, stream>>>(bsums, nblk);
  scan_add_kernel<<<nblk, 256, 0, stream>>>(row_ptr, fill, bsums, N);
  fill_kernel<<<(E + 255) / 256, 256, 0, stream>>>(row, col, fill, srcs, E);

  dim3 g2((N + BM - 1) / BM, 2);  // 256 output cols
  dim3 g1((N + BM - 1) / BM, 1);  // 64 output cols

  // layer 1: x -> B -> A (ReLU)
  gemm_kernel<<<g2, 256, 0, stream>>>(x, W1, B, N, 256, 256);
  aggregate_kernel<4, true><<<N, 64, 0, stream>>>(B, A, row_ptr, cnt, srcs, dinv, b1, 256);
  // layers 2..5 (shared W2)
  for (int l = 0; l < 4; ++l) {
    gemm_kernel<<<g2, 256, 0, stream>>>(A, W2, B, N, 256, 256);
    aggregate_kernel<4, true><<<N, 64, 0, stream>>>(B, A, row_ptr, cnt, srcs, dinv, b2, 256);
  }
  // layer 6: 256 -> 64, no ReLU
  gemm_kernel<<<g1, 256, 0, stream>>>(A, W3, B, N, 256, 64);
  aggregate_kernel<1, false><<<N, 64, 0, stream>>>(B, A, row_ptr, cnt, srcs, dinv, b3, 64);
  // final dense + sigmoid
  final_kernel<<<(N + 31) / 32, 256, 0, stream>>>(A, W4, b4, outp, N);
}

// Round 2
// 737.009 us; speedup vs baseline: 2.0447x; 2.0447x over previous
//
#include <hip/hip_runtime.h>
#include <hip/hip_bf16.h>
#include <math.h>

#define N_NODES 50000
#define N_EDGES 800000
#define GK 256  // K dim of all MFMA GEMMs

typedef unsigned short US;
typedef __attribute__((ext_vector_type(8))) short short8;
typedef __attribute__((ext_vector_type(4))) float floatx4;

static __device__ __forceinline__ float bflo(unsigned int u) {
  union { unsigned int i; float f; } c; c.i = u << 16; return c.f;
}
static __device__ __forceinline__ float bfhi(unsigned int u) {
  union { unsigned int i; float f; } c; c.i = u & 0xffff0000u; return c.f;
}
static __device__ __forceinline__ float bf2f(US u) {
  union { unsigned int i; float f; } c; c.i = ((unsigned int)u) << 16; return c.f;
}
static __device__ __forceinline__ US f2bf(float f) {  // round-to-nearest-even
  union { float f; unsigned int i; } c; c.f = f;
  unsigned int x = c.i;
  return (US)((x + 0x7fffu + ((x >> 16) & 1u)) >> 16);
}

// ----------------- preprocessing: degree + CSR build -----------------

__global__ void count_kernel(const int* __restrict__ col, int* __restrict__ cnt, int E) {
  int e = blockIdx.x * blockDim.x + threadIdx.x;
  if (e < E) atomicAdd(&cnt[col[e]], 1);
}

__global__ void dinv_kernel(const int* __restrict__ cnt, float* __restrict__ dinv, int n) {
  int j = blockIdx.x * blockDim.x + threadIdx.x;
  if (j < n) dinv[j] = 1.0f / sqrtf((float)(cnt[j] + 1));  // +1 self-loop; deg>=1 always
}

__global__ void scan_block_kernel(const int* __restrict__ in, int* __restrict__ out,
                                  int* __restrict__ bsums, int n) {
  __shared__ int s[256];
  int gid = blockIdx.x * 256 + threadIdx.x;
  int v = (gid < n) ? in[gid] : 0;
  s[threadIdx.x] = v;
  __syncthreads();
  for (int off = 1; off < 256; off <<= 1) {
    int t = (threadIdx.x >= off) ? s[threadIdx.x - off] : 0;
    __syncthreads();
    s[threadIdx.x] += t;
    __syncthreads();
  }
  if (gid < n) out[gid] = s[threadIdx.x] - v;  // exclusive
  if (threadIdx.x == 255) bsums[blockIdx.x] = s[255];
}

__global__ void scan_top_kernel(int* __restrict__ bsums, int n) {
  __shared__ int s[256];
  int v = (threadIdx.x < n) ? bsums[threadIdx.x] : 0;
  s[threadIdx.x] = v;
  __syncthreads();
  for (int off = 1; off < 256; off <<= 1) {
    int t = (threadIdx.x >= off) ? s[threadIdx.x - off] : 0;
    __syncthreads();
    s[threadIdx.x] += t;
    __syncthreads();
  }
  if (threadIdx.x < n) bsums[threadIdx.x] = s[threadIdx.x] - v;
}

__global__ void scan_add_kernel(int* __restrict__ row_ptr, int* __restrict__ fill,
                                const int* __restrict__ bsums, int n) {
  int gid = blockIdx.x * 256 + threadIdx.x;
  if (gid < n) {
    int v = row_ptr[gid] + bsums[blockIdx.x];
    row_ptr[gid] = v;
    fill[gid] = v;
  }
}

__global__ void fill_kernel(const int* __restrict__ row, const int* __restrict__ col,
                            int* __restrict__ fill, int* __restrict__ srcs, int E) {
  int e = blockIdx.x * blockDim.x + threadIdx.x;
  if (e < E) {
    int d = col[e];
    int pos = atomicAdd(&fill[d], 1);
    srcs[pos] = row[e];
  }
}

// ----------------- dtype conversion -----------------

__global__ void cvt_x_kernel(const float* __restrict__ x, US* __restrict__ xb, int n4) {
  int idx = blockIdx.x * 256 + threadIdx.x;
  if (idx < n4) {
    float4 v = *(const float4*)(x + (size_t)idx * 4);
    US o[4] = { f2bf(v.x), f2bf(v.y), f2bf(v.z), f2bf(v.w) };
    *(ushort4*)(xb + (size_t)idx * 4) = *(ushort4*)o;
  }
}

// W [K][Nc] fp32 -> Wt [Nc][K] bf16 (transposed so GEMM B-fragments are k-contiguous)
__global__ void cvt_w_kernel(const float* __restrict__ W, US* __restrict__ Wt, int K, int Nc) {
  int idx = blockIdx.x * 256 + threadIdx.x;
  if (idx < K * Nc) {
    int k = idx / Nc, n = idx % Nc;
    Wt[(size_t)n * K + k] = f2bf(W[idx]);
  }
}

// ----------------- bf16 MFMA GEMM: C[M,Nc] = A[M,256] @ Wt[Nc,256]^T -----------------
// 128x128 tile, 4 waves (2x2 of 64x64), 4x4 16x16x32 fragments per wave, BK=32.
// BN_VALID=64 path zero-fills Wt rows >=64 (layer 6, Nc=64).

template <int BN_VALID>
__global__ __launch_bounds__(256) void gemm_bf16_kernel(
    const US* __restrict__ A, const US* __restrict__ Wt,
    US* __restrict__ C, int M, int Nc) {
  constexpr int LDA = 40;  // 32 + 8 pad (keeps 16B align, spreads banks)
  __shared__ __align__(16) US As[128 * LDA];
  __shared__ __align__(16) US Bs[128 * LDA];
  int tid = threadIdx.x;
  int bm = blockIdx.x * 128;
  int bn = blockIdx.y * 128;
  int lane = tid & 63;
  int w = tid >> 6;
  int wr = (w & 1) * 64, wc = (w >> 1) * 64;
  int lm = lane & 15, lk = lane >> 4;

  floatx4 zero = {0.f, 0.f, 0.f, 0.f};
  floatx4 acc[4][4];
#pragma unroll
  for (int i = 0; i < 4; ++i)
#pragma unroll
    for (int j = 0; j < 4; ++j) acc[i][j] = zero;

  for (int k0 = 0; k0 < GK; k0 += 32) {
#pragma unroll
    for (int it = 0; it < 2; ++it) {
      int idx = tid + it * 256;
      int r = idx >> 2;          // 0..127
      int kc = (idx & 3) * 8;    // bf16 elem offset 0,8,16,24
      uint4 va = {0, 0, 0, 0};
      int gr = bm + r;
      if (gr < M) va = *(const uint4*)(A + (size_t)gr * GK + k0 + kc);
      *(uint4*)&As[r * LDA + kc] = va;
      uint4 vb = {0, 0, 0, 0};
      if (BN_VALID == 128 || r < BN_VALID)
        vb = *(const uint4*)(Wt + (size_t)(bn + r) * GK + k0 + kc);
      *(uint4*)&Bs[r * LDA + kc] = vb;
    }
    __syncthreads();
    short8 af[4], bfr[4];
#pragma unroll
    for (int i = 0; i < 4; ++i)
      af[i] = *(const short8*)&As[(wr + i * 16 + lm) * LDA + lk * 8];
#pragma unroll
    for (int j = 0; j < 4; ++j)
      bfr[j] = *(const short8*)&Bs[(wc + j * 16 + lm) * LDA + lk * 8];
#pragma unroll
    for (int i = 0; i < 4; ++i)
#pragma unroll
      for (int j = 0; j < 4; ++j)
        acc[i][j] = __builtin_amdgcn_mfma_f32_16x16x32_bf16(af[i], bfr[j], acc[i][j], 0, 0, 0);
    __syncthreads();
  }

  // C/D layout: col = lane&15, row = (lane>>4)*4 + reg  [m89/m91-verified]
#pragma unroll
  for (int i = 0; i < 4; ++i)
#pragma unroll
    for (int j = 0; j < 4; ++j) {
      int col = bn + wc + j * 16 + lm;
#pragma unroll
      for (int r = 0; r < 4; ++r) {
        int m = bm + wr + i * 16 + lk * 4 + r;
        if (m < M && col < Nc) C[(size_t)m * Nc + col] = f2bf(acc[i][j][r]);
      }
    }
}

// ----------------- pull aggregation, bf16 rows, fp32 accumulate -----------------
// out[j] = relu?( dinv[j]*(sum_src t[s]*dinv[s] + t[j]*dinv[j]) + bias )

template <bool RELU>
__global__ __launch_bounds__(64) void agg256_kernel(
    const US* __restrict__ t, US* __restrict__ out,
    const int* __restrict__ row_ptr, const int* __restrict__ cnt,
    const int* __restrict__ srcs, const float* __restrict__ dinv,
    const float* __restrict__ bias) {
  int j = blockIdx.x;
  int lane = threadIdx.x;
  int base = lane * 4;
  int start = row_ptr[j];
  int n = cnt[j];
  float a0 = 0.f, a1 = 0.f, a2 = 0.f, a3 = 0.f;
  int i = 0;
  for (; i + 1 < n; i += 2) {
    int s0 = srcs[start + i], s1 = srcs[start + i + 1];
    float w0 = dinv[s0], w1 = dinv[s1];
    uint2 v0 = *(const uint2*)(t + (size_t)s0 * 256 + base);
    uint2 v1 = *(const uint2*)(t + (size_t)s1 * 256 + base);
    a0 += bflo(v0.x) * w0; a1 += bfhi(v0.x) * w0;
    a2 += bflo(v0.y) * w0; a3 += bfhi(v0.y) * w0;
    a0 += bflo(v1.x) * w1; a1 += bfhi(v1.x) * w1;
    a2 += bflo(v1.y) * w1; a3 += bfhi(v1.y) * w1;
  }
  if (i < n) {
    int s0 = srcs[start + i];
    float w0 = dinv[s0];
    uint2 v0 = *(const uint2*)(t + (size_t)s0 * 256 + base);
    a0 += bflo(v0.x) * w0; a1 += bfhi(v0.x) * w0;
    a2 += bflo(v0.y) * w0; a3 += bfhi(v0.y) * w0;
  }
  float dj = dinv[j];
  uint2 vj = *(const uint2*)(t + (size_t)j * 256 + base);
  float r0 = (a0 + bflo(vj.x) * dj) * dj + bias[base + 0];
  float r1 = (a1 + bfhi(vj.x) * dj) * dj + bias[base + 1];
  float r2 = (a2 + bflo(vj.y) * dj) * dj + bias[base + 2];
  float r3 = (a3 + bfhi(vj.y) * dj) * dj + bias[base + 3];
  if (RELU) {
    r0 = fmaxf(r0, 0.f); r1 = fmaxf(r1, 0.f);
    r2 = fmaxf(r2, 0.f); r3 = fmaxf(r3, 0.f);
  }
  unsigned int o0 = ((unsigned int)f2bf(r1) << 16) | f2bf(r0);
  unsigned int o1 = ((unsigned int)f2bf(r3) << 16) | f2bf(r2);
  *(uint2*)(out + (size_t)j * 256 + base) = make_uint2(o0, o1);
}

// D=64 variant: bf16 in, fp32 out (feeds final dense layer), no relu
__global__ __launch_bounds__(64) void agg64_kernel(
    const US* __restrict__ t, float* __restrict__ out,
    const int* __restrict__ row_ptr, const int* __restrict__ cnt,
    const int* __restrict__ srcs, const float* __restrict__ dinv,
    const float* __restrict__ bias) {
  int j = blockIdx.x;
  int lane = threadIdx.x;
  int start = row_ptr[j];
  int n = cnt[j];
  float acc = 0.f;
  for (int i = 0; i < n; ++i) {
    int s = srcs[start + i];
    acc += bf2f(t[(size_t)s * 64 + lane]) * dinv[s];
  }
  float dj = dinv[j];
  float r = (acc + bf2f(t[(size_t)j * 64 + lane]) * dj) * dj + bias[lane];
  out[(size_t)j * 64 + lane] = r;
}

// ----------------- final dense: sigmoid(H[N,64] @ W4[64,64] + b4) -----------------

__global__ __launch_bounds__(256) void final_kernel(
    const float* __restrict__ H, const float* __restrict__ W4,
    const float* __restrict__ b4, float* __restrict__ out, int n) {
  __shared__ float Ws[64 * 64];
  __shared__ float bs[64];
  for (int i = threadIdx.x; i < 64 * 64; i += 256) Ws[i] = W4[i];
  if (threadIdx.x < 64) bs[threadIdx.x] = b4[threadIdx.x];
  __syncthreads();
  int wave = threadIdx.x >> 6;
  int lane = threadIdx.x & 63;
  int node0 = blockIdx.x * 32 + wave;
  for (int it = 0; it < 8; ++it) {
    int node = node0 + it * 4;
    if (node < n) {
      float a = H[(size_t)node * 64 + lane];
      float acc = bs[lane];
#pragma unroll
      for (int k = 0; k < 64; ++k) {
        float av = __shfl(a, k, 64);
        acc += av * Ws[k * 64 + lane];
      }
      out[(size_t)node * 64 + lane] = 1.0f / (1.0f + expf(-acc));
    }
  }
}

// ----------------- driver -----------------

extern "C" void kernel_launch(void* const* d_in, const int* in_sizes, int n_in,
                              void* d_out, int out_size, void* d_ws, size_t ws_size,
                              hipStream_t stream) {
  const float* x  = (const float*)d_in[0];
  const int* ei   = (const int*)d_in[1];
  const float* W1 = (const float*)d_in[2];
  const float* b1 = (const float*)d_in[3];
  const float* W2 = (const float*)d_in[4];
  const float* b2 = (const float*)d_in[5];
  const float* W3 = (const float*)d_in[6];
  const float* b3 = (const float*)d_in[7];
  const float* W4 = (const float*)d_in[8];
  const float* b4 = (const float*)d_in[9];
  float* outp = (float*)d_out;

  const int N = N_NODES, E = N_EDGES;
  const int* row = ei;
  const int* col = ei + E;

  // workspace layout (~68.3 MB)
  US* Ab = (US*)d_ws;                        // [N,256] bf16 ping
  US* Bb = Ab + (size_t)N * 256;             // [N,256] bf16 pong
  float* Afin = (float*)(Bb + (size_t)N * 256);  // [N,64] fp32
  float* dinv = Afin + (size_t)N * 64;
  int* cnt = (int*)(dinv + N);
  int* row_ptr = cnt + N;
  int* fill = row_ptr + N;
  int* bsums = fill + N;                     // [256]
  int* srcs = bsums + 256;                   // [E]
  US* Wt1 = (US*)(srcs + E);                 // [256,256] bf16 (transposed)
  US* Wt2 = Wt1 + 256 * 256;
  US* Wt3 = Wt2 + 256 * 256;                 // [64,256]

  hipMemsetAsync(cnt, 0, N * sizeof(int), stream);
  count_kernel<<<(E + 255) / 256, 256, 0, stream>>>(col, cnt, E);
  dinv_kernel<<<(N + 255) / 256, 256, 0, stream>>>(cnt, dinv, N);
  int nblk = (N + 255) / 256;
  scan_block_kernel<<<nblk, 256, 0, stream>>>(cnt, row_ptr, bsums, N);
  scan_top_kernel<<<1, 256, 0, stream>>>(bsums, nblk);
  scan_add_kernel<<<nblk, 256, 0, stream>>>(row_ptr, fill, bsums, N);
  fill_kernel<<<(E + 255) / 256, 256, 0, stream>>>(row, col, fill, srcs, E);

  cvt_x_kernel<<<(N * 256 / 4 + 255) / 256, 256, 0, stream>>>(x, Ab, N * 256 / 4);
  cvt_w_kernel<<<(256 * 256 + 255) / 256, 256, 0, stream>>>(W1, Wt1, 256, 256);
  cvt_w_kernel<<<(256 * 256 + 255) / 256, 256, 0, stream>>>(W2, Wt2, 256, 256);
  cvt_w_kernel<<<(256 * 64 + 255) / 256, 256, 0, stream>>>(W3, Wt3, 256, 64);

  dim3 g2((N + 127) / 128, 2);
  dim3 g1((N + 127) / 128, 1);

  gemm_bf16_kernel<128><<<g2, 256, 0, stream>>>(Ab, Wt1, Bb, N, 256);
  agg256_kernel<true><<<N, 64, 0, stream>>>(Bb, Ab, row_ptr, cnt, srcs, dinv, b1);
  for (int l = 0; l < 4; ++l) {
    gemm_bf16_kernel<128><<<g2, 256, 0, stream>>>(Ab, Wt2, Bb, N, 256);
    agg256_kernel<true><<<N, 64, 0, stream>>>(Bb, Ab, row_ptr, cnt, srcs, dinv, b2);
  }
  gemm_bf16_kernel<64><<<g1, 256, 0, stream>>>(Ab, Wt3, Bb, N, 64);
  agg64_kernel<<<N, 64, 0, stream>>>(Bb, Afin, row_ptr, cnt, srcs, dinv, b3);
  final_kernel<<<(N + 31) / 32, 256, 0, stream>>>(Afin, W4, b4, outp, N);
}

// Round 3
// 674.269 us; speedup vs baseline: 2.2350x; 1.0930x over previous
//
#include <hip/hip_runtime.h>
#include <hip/hip_bf16.h>
#include <math.h>

#define N_NODES 50000
#define N_EDGES 800000
#define GK 256  // K dim of the 256-wide MFMA GEMMs

typedef unsigned short US;
typedef __attribute__((ext_vector_type(8))) short short8;
typedef __attribute__((ext_vector_type(4))) float floatx4;

static __device__ __forceinline__ float bflo(unsigned int u) {
  union { unsigned int i; float f; } c; c.i = u << 16; return c.f;
}
static __device__ __forceinline__ float bfhi(unsigned int u) {
  union { unsigned int i; float f; } c; c.i = u & 0xffff0000u; return c.f;
}
static __device__ __forceinline__ float bf2f(US u) {
  union { unsigned int i; float f; } c; c.i = ((unsigned int)u) << 16; return c.f;
}
static __device__ __forceinline__ US f2bf(float f) {  // round-to-nearest-even
  union { float f; unsigned int i; } c; c.f = f;
  unsigned int x = c.i;
  return (US)((x + 0x7fffu + ((x >> 16) & 1u)) >> 16);
}

// ----------------- preprocessing: degree + CSR build -----------------

__global__ void count_kernel(const int* __restrict__ col, int* __restrict__ cnt, int E) {
  int e = blockIdx.x * blockDim.x + threadIdx.x;
  if (e < E) atomicAdd(&cnt[col[e]], 1);
}

__global__ void dinv_kernel(const int* __restrict__ cnt, float* __restrict__ dinv, int n) {
  int j = blockIdx.x * blockDim.x + threadIdx.x;
  if (j < n) dinv[j] = 1.0f / sqrtf((float)(cnt[j] + 1));  // +1 self-loop; deg>=1 always
}

__global__ void scan_block_kernel(const int* __restrict__ in, int* __restrict__ out,
                                  int* __restrict__ bsums, int n) {
  __shared__ int s[256];
  int gid = blockIdx.x * 256 + threadIdx.x;
  int v = (gid < n) ? in[gid] : 0;
  s[threadIdx.x] = v;
  __syncthreads();
  for (int off = 1; off < 256; off <<= 1) {
    int t = (threadIdx.x >= off) ? s[threadIdx.x - off] : 0;
    __syncthreads();
    s[threadIdx.x] += t;
    __syncthreads();
  }
  if (gid < n) out[gid] = s[threadIdx.x] - v;  // exclusive
  if (threadIdx.x == 255) bsums[blockIdx.x] = s[255];
}

__global__ void scan_top_kernel(int* __restrict__ bsums, int n) {
  __shared__ int s[256];
  int v = (threadIdx.x < n) ? bsums[threadIdx.x] : 0;
  s[threadIdx.x] = v;
  __syncthreads();
  for (int off = 1; off < 256; off <<= 1) {
    int t = (threadIdx.x >= off) ? s[threadIdx.x - off] : 0;
    __syncthreads();
    s[threadIdx.x] += t;
    __syncthreads();
  }
  if (threadIdx.x < n) bsums[threadIdx.x] = s[threadIdx.x] - v;
}

__global__ void scan_add_kernel(int* __restrict__ row_ptr, int* __restrict__ fill,
                                const int* __restrict__ bsums, int n) {
  int gid = blockIdx.x * 256 + threadIdx.x;
  if (gid < n) {
    int v = row_ptr[gid] + bsums[blockIdx.x];
    row_ptr[gid] = v;
    fill[gid] = v;
  }
}

__global__ void fill_kernel(const int* __restrict__ row, const int* __restrict__ col,
                            int* __restrict__ fill, int* __restrict__ srcs, int E) {
  int e = blockIdx.x * blockDim.x + threadIdx.x;
  if (e < E) {
    int d = col[e];
    int pos = atomicAdd(&fill[d], 1);
    srcs[pos] = row[e];
  }
}

// ----------------- dtype conversion -----------------

__global__ void cvt_x_kernel(const float* __restrict__ x, US* __restrict__ xb, int n4) {
  int idx = blockIdx.x * 256 + threadIdx.x;
  if (idx < n4) {
    float4 v = *(const float4*)(x + (size_t)idx * 4);
    US o[4] = { f2bf(v.x), f2bf(v.y), f2bf(v.z), f2bf(v.w) };
    *(ushort4*)(xb + (size_t)idx * 4) = *(ushort4*)o;
  }
}

// W [K][Nc] fp32 -> Wt [Nc][K] bf16 (transposed so B-fragments are k-contiguous)
__global__ void cvt_w_kernel(const float* __restrict__ W, US* __restrict__ Wt, int K, int Nc) {
  int idx = blockIdx.x * 256 + threadIdx.x;
  if (idx < K * Nc) {
    int k = idx / Nc, n = idx % Nc;
    Wt[(size_t)n * K + k] = f2bf(W[idx]);
  }
}

// ----------------- bf16 MFMA GEMM: C[M,Nc] = A[M,256] @ Wt[Nc,256]^T -----------------
// 128x128 tile, 4 waves (2x2 of 64x64), 4x4 16x16x32 fragments per wave, BK=32.

template <int BN_VALID>
__global__ __launch_bounds__(256) void gemm_bf16_kernel(
    const US* __restrict__ A, const US* __restrict__ Wt,
    US* __restrict__ C, int M, int Nc) {
  constexpr int LDA = 40;  // 32 + 8 pad
  __shared__ __align__(16) US As[128 * LDA];
  __shared__ __align__(16) US Bs[128 * LDA];
  int tid = threadIdx.x;
  int bm = blockIdx.x * 128;
  int bn = blockIdx.y * 128;
  int lane = tid & 63;
  int w = tid >> 6;
  int wr = (w & 1) * 64, wc = (w >> 1) * 64;
  int lm = lane & 15, lk = lane >> 4;

  floatx4 zero = {0.f, 0.f, 0.f, 0.f};
  floatx4 acc[4][4];
#pragma unroll
  for (int i = 0; i < 4; ++i)
#pragma unroll
    for (int j = 0; j < 4; ++j) acc[i][j] = zero;

  for (int k0 = 0; k0 < GK; k0 += 32) {
#pragma unroll
    for (int it = 0; it < 2; ++it) {
      int idx = tid + it * 256;
      int r = idx >> 2;          // 0..127
      int kc = (idx & 3) * 8;    // bf16 elem offset 0,8,16,24
      uint4 va = {0, 0, 0, 0};
      int gr = bm + r;
      if (gr < M) va = *(const uint4*)(A + (size_t)gr * GK + k0 + kc);
      *(uint4*)&As[r * LDA + kc] = va;
      uint4 vb = {0, 0, 0, 0};
      if (BN_VALID == 128 || r < BN_VALID)
        vb = *(const uint4*)(Wt + (size_t)(bn + r) * GK + k0 + kc);
      *(uint4*)&Bs[r * LDA + kc] = vb;
    }
    __syncthreads();
    short8 af[4], bfr[4];
#pragma unroll
    for (int i = 0; i < 4; ++i)
      af[i] = *(const short8*)&As[(wr + i * 16 + lm) * LDA + lk * 8];
#pragma unroll
    for (int j = 0; j < 4; ++j)
      bfr[j] = *(const short8*)&Bs[(wc + j * 16 + lm) * LDA + lk * 8];
#pragma unroll
    for (int i = 0; i < 4; ++i)
#pragma unroll
      for (int j = 0; j < 4; ++j)
        acc[i][j] = __builtin_amdgcn_mfma_f32_16x16x32_bf16(af[i], bfr[j], acc[i][j], 0, 0, 0);
    __syncthreads();
  }

  // C/D layout: col = lane&15, row = (lane>>4)*4 + reg
#pragma unroll
  for (int i = 0; i < 4; ++i)
#pragma unroll
    for (int j = 0; j < 4; ++j) {
      int col = bn + wc + j * 16 + lm;
#pragma unroll
      for (int r = 0; r < 4; ++r) {
        int m = bm + wr + i * 16 + lk * 4 + r;
        if (m < M && col < Nc) C[(size_t)m * Nc + col] = f2bf(acc[i][j][r]);
      }
    }
}

// ----------------- pull aggregation, bf16 rows, fp32 accumulate -----------------
// out[j] = relu?( dinv[j]*(sum_src t[s]*dinv[s] + t[j]*dinv[j]) + bias )
// Unroll-4 edge loop: 4 independent src->dinv->row load chains in flight.

template <bool RELU>
__global__ __launch_bounds__(64) void agg256_kernel(
    const US* __restrict__ t, US* __restrict__ out,
    const int* __restrict__ row_ptr, const int* __restrict__ cnt,
    const int* __restrict__ srcs, const float* __restrict__ dinv,
    const float* __restrict__ bias) {
  int j = blockIdx.x;
  int lane = threadIdx.x;
  int base = lane * 4;
  int start = row_ptr[j];
  int n = cnt[j];
  float a0 = 0.f, a1 = 0.f, a2 = 0.f, a3 = 0.f;
  int i = 0;
  for (; i + 3 < n; i += 4) {
    int s0 = srcs[start + i + 0];
    int s1 = srcs[start + i + 1];
    int s2 = srcs[start + i + 2];
    int s3 = srcs[start + i + 3];
    float w0 = dinv[s0], w1 = dinv[s1], w2 = dinv[s2], w3 = dinv[s3];
    uint2 v0 = *(const uint2*)(t + (size_t)s0 * 256 + base);
    uint2 v1 = *(const uint2*)(t + (size_t)s1 * 256 + base);
    uint2 v2 = *(const uint2*)(t + (size_t)s2 * 256 + base);
    uint2 v3 = *(const uint2*)(t + (size_t)s3 * 256 + base);
    a0 += bflo(v0.x) * w0; a1 += bfhi(v0.x) * w0;
    a2 += bflo(v0.y) * w0; a3 += bfhi(v0.y) * w0;
    a0 += bflo(v1.x) * w1; a1 += bfhi(v1.x) * w1;
    a2 += bflo(v1.y) * w1; a3 += bfhi(v1.y) * w1;
    a0 += bflo(v2.x) * w2; a1 += bfhi(v2.x) * w2;
    a2 += bflo(v2.y) * w2; a3 += bfhi(v2.y) * w2;
    a0 += bflo(v3.x) * w3; a1 += bfhi(v3.x) * w3;
    a2 += bflo(v3.y) * w3; a3 += bfhi(v3.y) * w3;
  }
  for (; i < n; ++i) {
    int s0 = srcs[start + i];
    float w0 = dinv[s0];
    uint2 v0 = *(const uint2*)(t + (size_t)s0 * 256 + base);
    a0 += bflo(v0.x) * w0; a1 += bfhi(v0.x) * w0;
    a2 += bflo(v0.y) * w0; a3 += bfhi(v0.y) * w0;
  }
  float dj = dinv[j];
  uint2 vj = *(const uint2*)(t + (size_t)j * 256 + base);
  float r0 = (a0 + bflo(vj.x) * dj) * dj + bias[base + 0];
  float r1 = (a1 + bfhi(vj.x) * dj) * dj + bias[base + 1];
  float r2 = (a2 + bflo(vj.y) * dj) * dj + bias[base + 2];
  float r3 = (a3 + bfhi(vj.y) * dj) * dj + bias[base + 3];
  if (RELU) {
    r0 = fmaxf(r0, 0.f); r1 = fmaxf(r1, 0.f);
    r2 = fmaxf(r2, 0.f); r3 = fmaxf(r3, 0.f);
  }
  unsigned int o0 = ((unsigned int)f2bf(r1) << 16) | f2bf(r0);
  unsigned int o1 = ((unsigned int)f2bf(r3) << 16) | f2bf(r2);
  *(uint2*)(out + (size_t)j * 256 + base) = make_uint2(o0, o1);
}

// D=64 variant: bf16 in, bf16 out (feeds final MFMA layer), no relu
__global__ __launch_bounds__(64) void agg64_kernel(
    const US* __restrict__ t, US* __restrict__ out,
    const int* __restrict__ row_ptr, const int* __restrict__ cnt,
    const int* __restrict__ srcs, const float* __restrict__ dinv,
    const float* __restrict__ bias) {
  int j = blockIdx.x;
  int lane = threadIdx.x;
  int start = row_ptr[j];
  int n = cnt[j];
  float acc = 0.f;
  int i = 0;
  for (; i + 3 < n; i += 4) {
    int s0 = srcs[start + i + 0];
    int s1 = srcs[start + i + 1];
    int s2 = srcs[start + i + 2];
    int s3 = srcs[start + i + 3];
    acc += bf2f(t[(size_t)s0 * 64 + lane]) * dinv[s0];
    acc += bf2f(t[(size_t)s1 * 64 + lane]) * dinv[s1];
    acc += bf2f(t[(size_t)s2 * 64 + lane]) * dinv[s2];
    acc += bf2f(t[(size_t)s3 * 64 + lane]) * dinv[s3];
  }
  for (; i < n; ++i) {
    int s = srcs[start + i];
    acc += bf2f(t[(size_t)s * 64 + lane]) * dinv[s];
  }
  float dj = dinv[j];
  float r = (acc + bf2f(t[(size_t)j * 64 + lane]) * dj) * dj + bias[lane];
  out[(size_t)j * 64 + lane] = f2bf(r);
}

// ----------------- final dense: sigmoid(H[N,64] @ W4t[64,64]^T + b4), MFMA -----------------
// One wave per 16 rows; 4 col-tiles of 16; K=64 in two 32-steps. No LDS.
// A frag: lane(lm,lk) reads H[(m0+lm)*64 + ks*32 + lk*8] (8 contiguous bf16).
// B frag: lane(lm,lk) reads W4t[(j*16+lm)*64 + ks*32 + lk*8].

__global__ __launch_bounds__(256) void final_mfma_kernel(
    const US* __restrict__ H, const US* __restrict__ W4t,
    const float* __restrict__ b4, float* __restrict__ out, int M) {
  int wv = threadIdx.x >> 6, lane = threadIdx.x & 63;
  int m0 = blockIdx.x * 64 + wv * 16;
  if (m0 >= M) return;  // M % 16 == 0: waves are fully valid or fully out
  int lm = lane & 15, lk = lane >> 4;

  floatx4 zero = {0.f, 0.f, 0.f, 0.f};
  floatx4 acc[4] = {zero, zero, zero, zero};
#pragma unroll
  for (int ks = 0; ks < 2; ++ks) {
    short8 af = *(const short8*)&H[(size_t)(m0 + lm) * 64 + ks * 32 + lk * 8];
#pragma unroll
    for (int jt = 0; jt < 4; ++jt) {
      short8 bf = *(const short8*)&W4t[(size_t)(jt * 16 + lm) * 64 + ks * 32 + lk * 8];
      acc[jt] = __builtin_amdgcn_mfma_f32_16x16x32_bf16(af, bf, acc[jt], 0, 0, 0);
    }
  }
#pragma unroll
  for (int jt = 0; jt < 4; ++jt) {
    int col = jt * 16 + lm;
    float bv = b4[col];
#pragma unroll
    for (int r = 0; r < 4; ++r) {
      int m = m0 + lk * 4 + r;
      float v = acc[jt][r] + bv;
      out[(size_t)m * 64 + col] = 1.0f / (1.0f + expf(-v));
    }
  }
}

// ----------------- driver -----------------

extern "C" void kernel_launch(void* const* d_in, const int* in_sizes, int n_in,
                              void* d_out, int out_size, void* d_ws, size_t ws_size,
                              hipStream_t stream) {
  const float* x  = (const float*)d_in[0];
  const int* ei   = (const int*)d_in[1];
  const float* W1 = (const float*)d_in[2];
  const float* b1 = (const float*)d_in[3];
  const float* W2 = (const float*)d_in[4];
  const float* b2 = (const float*)d_in[5];
  const float* W3 = (const float*)d_in[6];
  const float* b3 = (const float*)d_in[7];
  const float* W4 = (const float*)d_in[8];
  const float* b4 = (const float*)d_in[9];
  float* outp = (float*)d_out;

  const int N = N_NODES, E = N_EDGES;
  const int* row = ei;
  const int* col = ei + E;

  // workspace layout (~62 MB)
  US* Ab = (US*)d_ws;                        // [N,256] bf16 ping
  US* Bb = Ab + (size_t)N * 256;             // [N,256] bf16 pong
  US* Hfin = Bb + (size_t)N * 256;           // [N,64] bf16 (final GEMM input)
  float* dinv = (float*)(Hfin + (size_t)N * 64);
  int* cnt = (int*)(dinv + N);
  int* row_ptr = cnt + N;
  int* fill = row_ptr + N;
  int* bsums = fill + N;                     // [256]
  int* srcs = bsums + 256;                   // [E]
  US* Wt1 = (US*)(srcs + E);                 // [256,256] bf16 (transposed)
  US* Wt2 = Wt1 + 256 * 256;
  US* Wt3 = Wt2 + 256 * 256;                 // [64,256]
  US* Wt4 = Wt3 + 64 * 256;                  // [64,64]

  hipMemsetAsync(cnt, 0, N * sizeof(int), stream);
  count_kernel<<<(E + 255) / 256, 256, 0, stream>>>(col, cnt, E);
  dinv_kernel<<<(N + 255) / 256, 256, 0, stream>>>(cnt, dinv, N);
  int nblk = (N + 255) / 256;
  scan_block_kernel<<<nblk, 256, 0, stream>>>(cnt, row_ptr, bsums, N);
  scan_top_kernel<<<1, 256, 0, stream>>>(bsums, nblk);
  scan_add_kernel<<<nblk, 256, 0, stream>>>(row_ptr, fill, bsums, N);
  fill_kernel<<<(E + 255) / 256, 256, 0, stream>>>(row, col, fill, srcs, E);

  cvt_x_kernel<<<(N * 256 / 4 + 255) / 256, 256, 0, stream>>>(x, Ab, N * 256 / 4);
  cvt_w_kernel<<<(256 * 256 + 255) / 256, 256, 0, stream>>>(W1, Wt1, 256, 256);
  cvt_w_kernel<<<(256 * 256 + 255) / 256, 256, 0, stream>>>(W2, Wt2, 256, 256);
  cvt_w_kernel<<<(256 * 64 + 255) / 256, 256, 0, stream>>>(W3, Wt3, 256, 64);
  cvt_w_kernel<<<(64 * 64 + 255) / 256, 256, 0, stream>>>(W4, Wt4, 64, 64);

  dim3 g2((N + 127) / 128, 2);
  dim3 g1((N + 127) / 128, 1);

  gemm_bf16_kernel<128><<<g2, 256, 0, stream>>>(Ab, Wt1, Bb, N, 256);
  agg256_kernel<true><<<N, 64, 0, stream>>>(Bb, Ab, row_ptr, cnt, srcs, dinv, b1);
  for (int l = 0; l < 4; ++l) {
    gemm_bf16_kernel<128><<<g2, 256, 0, stream>>>(Ab, Wt2, Bb, N, 256);
    agg256_kernel<true><<<N, 64, 0, stream>>>(Bb, Ab, row_ptr, cnt, srcs, dinv, b2);
  }
  gemm_bf16_kernel<64><<<g1, 256, 0, stream>>>(Ab, Wt3, Bb, N, 64);
  agg64_kernel<<<N, 64, 0, stream>>>(Bb, Hfin, row_ptr, cnt, srcs, dinv, b3);
  final_mfma_kernel<<<(N + 63) / 64, 256, 0, stream>>>(Hfin, Wt4, b4, outp, N);
}